// Round 11
// baseline (227.967 us; speedup 1.0000x reference)
//
#include <hip/hip_runtime.h>
#include <math.h>

typedef unsigned long long ull;

// ws byte offsets
#define H_BYTE     0          // ull[2][128][128] = 256 KB (h pairs)
#define IOUX_BYTE  262144     // float[2][16][128][64] = 1 MB (k1 -> k2)
#define FLAG_BYTE  1310720    // int prog[2][16]; fin[32] at ints 32..63

__device__ __forceinline__ float sigmf(float x){ return 1.0f/(1.0f+__expf(-x)); }
__device__ __forceinline__ float tanh_fast(float x){ float e=__expf(2.0f*x); return 1.0f-2.0f/(e+1.0f); }
__device__ __forceinline__ ull packf2(float lo, float hi){
    union{ float f[2]; ull u; } x; x.f[0]=lo; x.f[1]=hi; return x.u;
}
__device__ __forceinline__ ull aload64(const ull* p){
    return __hip_atomic_load(p, __ATOMIC_RELAXED, __HIP_MEMORY_SCOPE_AGENT);
}
__device__ __forceinline__ float aloadf(const float* p){
    return __hip_atomic_load(p, __ATOMIC_RELAXED, __HIP_MEMORY_SCOPE_AGENT);
}
__device__ __forceinline__ void astore64(ull* p, ull v){
    __hip_atomic_store(p, v, __ATOMIC_RELAXED, __HIP_MEMORY_SCOPE_AGENT);
}
__device__ __forceinline__ int aload32(const int* p){
    return __hip_atomic_load(p, __ATOMIC_RELAXED, __HIP_MEMORY_SCOPE_AGENT);
}
__device__ __forceinline__ void astore32(int* p, int v){
    __hip_atomic_store(p, v, __ATOMIC_RELAXED, __HIP_MEMORY_SCOPE_AGENT);
}

// 8 pipelined MALL-coherent 16B loads, one waitcnt (proven in R9).
__device__ __forceinline__ void stage8(const ull* p0, const ull* p1, const ull* p2, const ull* p3,
                                       const ull* p4, const ull* p5, const ull* p6, const ull* p7,
                                       float4* r){
    asm volatile(
        "global_load_dwordx4 %0, %8, off sc0 sc1\n\t"
        "global_load_dwordx4 %1, %9, off sc0 sc1\n\t"
        "global_load_dwordx4 %2, %10, off sc0 sc1\n\t"
        "global_load_dwordx4 %3, %11, off sc0 sc1\n\t"
        "global_load_dwordx4 %4, %12, off sc0 sc1\n\t"
        "global_load_dwordx4 %5, %13, off sc0 sc1\n\t"
        "global_load_dwordx4 %6, %14, off sc0 sc1\n\t"
        "global_load_dwordx4 %7, %15, off sc0 sc1\n\t"
        "s_waitcnt vmcnt(0)"
        : "=&v"(r[0]), "=&v"(r[1]), "=&v"(r[2]), "=&v"(r[3]),
          "=&v"(r[4]), "=&v"(r[5]), "=&v"(r[6]), "=&v"(r[7])
        : "v"(p0), "v"(p1), "v"(p2), "v"(p3), "v"(p4), "v"(p5), "v"(p6), "v"(p7)
        : "memory");
    __builtin_amdgcn_sched_barrier(0);
}

// ---------------------------------------------------------------------------
// K1: input GEMM. 128 blocks = tree(2) x sub(16) x q(4); 256 threads.
// dst[tree*16+sub][node][64]: cols 0..47 = i|o|u (16 each), 48..63 = fx.
// ---------------------------------------------------------------------------
__global__ __launch_bounds__(256) void k1_gemm(
        const float* __restrict__ emb,
        const float* __restrict__ Wioux, const float* __restrict__ bioux,
        const float* __restrict__ Wfx,   const float* __restrict__ bfx,
        const int* __restrict__ linputs, const int* __restrict__ rinputs,
        float* __restrict__ ws){
    int bid  = blockIdx.x;
    int tree = bid >> 6;
    int sub  = (bid >> 2) & 15;
    int q    = bid & 3;
    int n0   = q * 32;
    const int* inp = tree ? rinputs : linputs;
    float* dst = (float*)((char*)ws + IOUX_BYTE) + (size_t)(tree*16+sub)*128*64;

    __shared__ float Xs[32][513];
    __shared__ int toks[32];
    int tid = threadIdx.x;
    if (tid < 32) toks[tid] = inp[n0 + tid];
    __syncthreads();
    {
        int r = tid & 31, seg = tid >> 5;
        const float* src = emb + (size_t)toks[r]*512 + seg*64;
        #pragma unroll
        for (int ii = 0; ii < 16; ii++){
            float4 v = ((const float4*)src)[ii];
            Xs[r][seg*64 + ii*4 + 0] = v.x;
            Xs[r][seg*64 + ii*4 + 1] = v.y;
            Xs[r][seg*64 + ii*4 + 2] = v.z;
            Xs[r][seg*64 + ii*4 + 3] = v.w;
        }
    }
    __syncthreads();
    int c  = tid & 63;
    int ng = tid >> 6;
    int g = c >> 4, jj = c & 15;
    const float* Wcol; int ld; float bias;
    if (g < 3){ int col = g*256 + sub*16 + jj; Wcol = Wioux + col; ld = 768; bias = bioux[col]; }
    else      { int col = sub*16 + jj;         Wcol = Wfx + col;   ld = 256; bias = bfx[col]; }
    float acc[8] = {0,0,0,0,0,0,0,0};
    #pragma unroll 4
    for (int k = 0; k < 512; k++){
        float w = Wcol[(size_t)k*ld];
        #pragma unroll
        for (int i = 0; i < 8; i++) acc[i] = fmaf(Xs[ng*8+i][k], w, acc[i]);
    }
    #pragma unroll
    for (int i = 0; i < 8; i++)
        dst[(size_t)(n0 + ng*8 + i)*64 + c] = acc[i] + bias;
}

// ---------------------------------------------------------------------------
// K2: dataflow TreeLSTM. 32 blocks (16/tree) x 256 threads, fused head.
// Thread map: cj = tid>>4 (col in slice), kg = tid&15 (k-group / node slot).
// 16-way k-reduce = in-wave shfl_xor 1/2/4/8 (no LDS round trip).
// Schedule fully precomputed in prologue; ~4 syncs per batch.
// ---------------------------------------------------------------------------
#define MAXB 136

__global__ __launch_bounds__(256, 1) void k2_scan(
        const float* __restrict__ Wiouh, const float* __restrict__ biouh,
        const float* __restrict__ Wfh,   const float* __restrict__ bfh,
        const int* __restrict__ lparents, const int* __restrict__ rparents,
        const float* __restrict__ Wattn, const float* __restrict__ battn,
        const float* __restrict__ Wwh,   const float* __restrict__ bwh,
        const float* __restrict__ Wwp,   const float* __restrict__ bwp,
        float* __restrict__ ws, float* __restrict__ out){

    int bid = blockIdx.x;
    int tree = bid >> 4;
    int sub  = bid & 15;
    int slice = sub * 16;
    const int* parents = tree ? rparents : lparents;

    ull* H2all = (ull*)((char*)ws + H_BYTE);
    ull* H2 = H2all + (size_t)tree*128*128;
    const float* iosrc = (const float*)((char*)ws + IOUX_BYTE) + (size_t)(tree*16+sub)*128*64;
    int* flagB = (int*)((char*)ws + FLAG_BYTE);
    int* prog  = flagB + tree*16;
    int* fin   = flagB + 32;

    // km(k) = (k>>4)*20 + (k&15); row pitch 324 (16B-aligned, 2-way banks max)
    __shared__ float hv[32][324];
    __shared__ float hsin[16][324];
    __shared__ float FCtmp[32][17];
    __shared__ float cc[128][17];
    __shared__ float ioufL[128][68];
    __shared__ int par[128], rnd[128], order[128], kids[128], rankOf[128], posOf[128];
    __shared__ int rstart[129], kstart[129], cnt[129];
    __shared__ int bStart[MAXB], bN[MAXB], bM[MAXB], bCbase[MAXB], bLevel[MAXB];
    __shared__ int bFirst[128];
    __shared__ int sCoff[MAXB][17];
    __shared__ int sClist[128];
    __shared__ int changed, nbS;

    int tid = threadIdx.x;
    int cj = tid >> 4;      // col within slice
    int kg = tid & 15;      // k-group / node slot
    int jcol = slice + cj;

    // ---- weights -> registers ----
    float Wi[16], Wo[16], Wu[16], Wf[16];
    #pragma unroll
    for (int kk = 0; kk < 16; kk++){
        int k = kg*16 + kk;
        Wi[kk] = Wiouh[(size_t)k*768 + jcol];
        Wo[kk] = Wiouh[(size_t)k*768 + 256 + jcol];
        Wu[kk] = Wiouh[(size_t)k*768 + 512 + jcol];
        Wf[kk] = Wfh[(size_t)k*256 + jcol];
    }
    float bioI = biouh[jcol], bioO = biouh[256+jcol], bioU = biouh[512+jcol];
    float bfv  = bfh[jcol];

    // ---- iou/fx slice -> LDS ----
    for (int i = tid; i < 128*16; i += 256){
        int n = i >> 4, f4 = i & 15;
        float4 v = ((const float4*)(iosrc + (size_t)n*64))[f4];
        int c0 = f4*4;
        ioufL[n][c0+0]=v.x; ioufL[n][c0+1]=v.y; ioufL[n][c0+2]=v.z; ioufL[n][c0+3]=v.w;
    }

    // ---- tree structure (block-local, deterministic) ----
    if (tid < 128){ par[tid] = parents[tid]; rnd[tid] = 0; }
    __syncthreads();
    for(;;){
        if (tid==0) changed = 0;
        __syncthreads();
        if (tid < 128){
            int p = par[tid];
            if (p < 128){
                int v = rnd[tid] + 1;
                if (atomicMax(&rnd[p], v) < v) changed = 1;
            }
        }
        __syncthreads();
        int done = (changed == 0);
        __syncthreads();
        if (done) break;
    }
    int nr = rnd[127] + 1;

    if (tid <= 128) cnt[tid] = 0;
    __syncthreads();
    if (tid < 128) atomicAdd(&cnt[rnd[tid]], 1);
    __syncthreads();
    if (tid==0){ int s2=0; for(int r2=0;r2<128;r2++){ rstart[r2]=s2; s2+=cnt[r2]; } rstart[128]=s2; }
    __syncthreads();
    if (tid < 128){
        int r2 = rnd[tid], rk = 0;
        for (int t2 = 0; t2 < tid; t2++) rk += (rnd[t2]==r2);
        int pos = rstart[r2]+rk;
        order[pos] = tid;
        posOf[tid] = pos;
    }
    __syncthreads();
    if (tid <= 128) cnt[tid] = 0;
    __syncthreads();
    if (tid < 128) atomicAdd(&cnt[par[tid]], 1);
    __syncthreads();
    if (tid==0){ int s2=0; for(int t2=0;t2<=128;t2++){ kstart[t2]=s2; s2+=cnt[t2]; } }
    __syncthreads();
    if (tid < 128){
        int p = par[tid], rk = 0;
        for (int t2 = 0; t2 < tid; t2++) rk += (par[t2]==p);
        kids[kstart[p]+rk] = tid;
        rankOf[tid] = rk;
    }
    __syncthreads();

    // ---- schedule build (once) ----
    if (tid == 0){
        int nb = 0;
        for (int r = 0; r < nr; r++){
            bFirst[r] = nb;
            for (int b0 = rstart[r]; b0 < rstart[r+1]; b0 += 16){
                int nn = rstart[r+1] - b0; if (nn > 16) nn = 16;
                bStart[nb] = b0; bN[nb] = nn; bLevel[nb] = r; nb++;
            }
        }
        nbS = nb;
    }
    __syncthreads();
    int NB = nbS;
    if (tid < NB){
        int base = 0;
        for (int s = 0; s < 16; s++){
            sCoff[tid][s] = base;
            if (s < bN[tid]){
                int t = order[bStart[tid] + s];
                base += kstart[t+1] - kstart[t];
            }
        }
        sCoff[tid][16] = base;
        bM[tid] = base;
    }
    __syncthreads();
    if (tid == 0){ int acc = 0; for (int b = 0; b < NB; b++){ bCbase[b] = acc; acc += bM[b]; } }
    __syncthreads();
    if (tid < 128){
        int p = par[tid];
        if (p < 128){
            int rp = rnd[p];
            int idx = posOf[p] - rstart[rp];
            int bb = bFirst[rp] + (idx >> 4);
            int sp = idx & 15;
            sClist[bCbase[bb] + sCoff[bb][sp] + rankOf[tid]] = tid;
        }
    }
    __syncthreads();

    // ---- main batch loop ----
    int seenV = 0;   // poll cache (lanes tid<16)
    for (int b = 0; b < NB; b++){
        int lev = bLevel[b];
        int n0 = bStart[b], nn = bN[b];
        int t = (kg < nn) ? order[n0 + kg] : -1;
        float h = 0.f;

        if (lev == 0){
            if (t >= 0){
                float iv = ioufL[t][cj]    + bioI;
                float ov = ioufL[t][16+cj] + bioO;
                float uv = ioufL[t][32+cj] + bioU;
                float cv = sigmf(iv) * tanh_fast(uv);
                h = sigmf(ov) * tanh_fast(cv);
                cc[t][cj] = cv;
            }
        } else {
            // readiness: all level-(lev-1) and earlier positions published
            int need = rstart[lev];
            if (tid < 16 && seenV < need){
                for(;;){
                    seenV = aload32(&prog[tid]);
                    if (seenV >= need) break;
                    __builtin_amdgcn_s_sleep(1);
                }
            }
            __syncthreads();

            int M = bM[b], cbase = bCbase[b];
            int o0 = sCoff[b][kg], o1 = sCoff[b][kg+1];
            float fc = 0.f;
            bool first = true;

            for (int cb = 0; cb < M; cb += 32){
                int mm = M - cb; if (mm > 32) mm = 32;
                {   // stage rows: lane-major pipelined loads
                    int c16 = tid & 63, rw = tid >> 6;
                    int k0 = c16*4, km = (k0>>4)*20 + (k0&15);
                    const ull* pp[8];
                    #pragma unroll
                    for (int p = 0; p < 8; p++){
                        int s = p*4 + rw;
                        int idx = (s < mm) ? sClist[cbase+cb+s] : sClist[cbase+cb];
                        pp[p] = H2 + (size_t)idx*128 + c16*2;
                    }
                    float4 rr[8];
                    stage8(pp[0],pp[1],pp[2],pp[3],pp[4],pp[5],pp[6],pp[7], rr);
                    #pragma unroll
                    for (int p = 0; p < 8; p++){
                        int s = p*4 + rw;
                        if (s < mm) *(float4*)&hv[s][km] = rr[p];
                    }
                }
                __syncthreads();

                // f matvec: in-wave 16-way reduce; keep on owner thread
                float fs0 = 0.f, fs1 = 0.f;
                #pragma unroll
                for (int s = 0; s < 32; s++){
                    if (s < mm){
                        const float* row = &hv[s][kg*20];
                        float acc2 = 0.f;
                        #pragma unroll
                        for (int kk = 0; kk < 16; kk++) acc2 = fmaf(Wf[kk], row[kk], acc2);
                        acc2 += __shfl_xor(acc2, 1);
                        acc2 += __shfl_xor(acc2, 2);
                        acc2 += __shfl_xor(acc2, 4);
                        acc2 += __shfl_xor(acc2, 8);
                        if (kg == (s & 15)){ if (s < 16) fs0 = acc2; else fs1 = acc2; }
                    }
                }
                // f gates -> FCtmp (thread (cj,kg) owns slots kg and kg+16)
                {
                    int s = kg;
                    if (s < mm){
                        int c = sClist[cbase+cb+s]; int p = par[c];
                        float f = sigmf(fs0 + bfv + ioufL[p][48+cj]);
                        FCtmp[s][cj] = f * cc[c][cj];
                    }
                    s = kg + 16;
                    if (s < mm){
                        int c = sClist[cbase+cb+s]; int p = par[c];
                        float f = sigmf(fs1 + bfv + ioufL[p][48+cj]);
                        FCtmp[s][cj] = f * cc[c][cj];
                    }
                }
                __syncthreads();

                // accumulate: thread (cj,kg) -> hsin[slot kg][group cj]
                {
                    int a0 = o0 > cb ? o0 : cb;
                    int a1 = o1 < cb+mm ? o1 : cb+mm;
                    float* dst = &hsin[kg][cj*20];
                    for (int o = a0; o < a1; o++){
                        int s = o - cb;
                        const float* src = &hv[s][cj*20];
                        if (first){
                            #pragma unroll
                            for (int kk = 0; kk < 16; kk++) dst[kk] = src[kk];
                            first = false;
                        } else {
                            #pragma unroll
                            for (int kk = 0; kk < 16; kk++) dst[kk] += src[kk];
                        }
                        fc += FCtmp[s][cj];
                    }
                }
                __syncthreads();
            }

            // iou matvec: in-wave reduce; keep slot kg's gates in registers
            float gx = 0.f, gy = 0.f, gz = 0.f;
            #pragma unroll
            for (int n = 0; n < 16; n++){
                const float* row = &hsin[n][kg*20];
                float x = 0.f, y = 0.f, z = 0.f;
                #pragma unroll
                for (int kk = 0; kk < 16; kk++){
                    float v = row[kk];
                    x = fmaf(Wi[kk], v, x);
                    y = fmaf(Wo[kk], v, y);
                    z = fmaf(Wu[kk], v, z);
                }
                x += __shfl_xor(x,1); x += __shfl_xor(x,2); x += __shfl_xor(x,4); x += __shfl_xor(x,8);
                y += __shfl_xor(y,1); y += __shfl_xor(y,2); y += __shfl_xor(y,4); y += __shfl_xor(y,8);
                z += __shfl_xor(z,1); z += __shfl_xor(z,2); z += __shfl_xor(z,4); z += __shfl_xor(z,8);
                if (kg == n){ gx = x; gy = y; gz = z; }
            }
            if (t >= 0){
                float iv = gx + ioufL[t][cj]    + bioI;
                float ov = gy + ioufL[t][16+cj] + bioO;
                float uv = gz + ioufL[t][32+cj] + bioU;
                float cv = fmaf(sigmf(iv), tanh_fast(uv), fc);
                h = sigmf(ov) * tanh_fast(cv);
                cc[t][cj] = cv;
            }
        }

        // publish h (pack col pairs: cj and cj^1 differ by lane bit 4)
        float hp = __shfl_xor(h, 16);
        if (t >= 0 && (cj & 1) == 0)
            astore64(&H2[(size_t)t*128 + (slice>>1) + (cj>>1)], packf2(h, hp));
        __syncthreads();   // drain publishes; protect LDS reuse
        if (tid == 0) astore32(&prog[sub], n0 + nn);
    }

    // ---- fin + fused head (block 0) ----
    if (tid == 0) astore32(&fin[bid], 1);
    if (bid != 0) return;
    if (tid < 64){
        for(;;){
            int v = (tid < 32) ? aload32(&fin[tid]) : 1;
            if (__all((tid < 32) ? (v == 1) : 1)) break;
            __builtin_amdgcn_s_sleep(2);
        }
    }
    __syncthreads();

    float* F  = &hv[0][0];
    float* rl = F,        *rr  = F + 256;
    float* sA = F + 512,  *sB  = F + 640;
    float* bet= F + 768,  *alp = F + 1024;
    float* vl = F + 1280, *vr  = F + 1536;
    float* vec= F + 1792, *hid = F + 2304;
    const ull* HuL = H2all;
    const ull* HuR = H2all + (size_t)128*128;

    {   // roots
        union{ ull u; float f[2]; } w2;
        if (tid < 128){
            w2.u = aload64(&HuL[(size_t)127*128 + tid]);
            rl[2*tid] = w2.f[0]; rl[2*tid+1] = w2.f[1];
        } else {
            int p = tid - 128;
            w2.u = aload64(&HuR[(size_t)127*128 + p]);
            rr[2*p] = w2.f[0]; rr[2*p+1] = w2.f[1];
        }
    }
    __syncthreads();
    {   // sA[i] = Hl_root . Hr[i] ; sB[i] = Hl[i] . Hr_root
        int i = tid & 127;
        const ull* row = (tid < 128) ? &HuR[(size_t)i*128] : &HuL[(size_t)i*128];
        const float* rt = (tid < 128) ? rl : rr;
        float acc2 = 0.f;
        for (int p0 = 0; p0 < 128; p0 += 16){
            ull u[16];
            #pragma unroll
            for (int q2 = 0; q2 < 16; q2++) u[q2] = aload64(&row[p0+q2]);
            #pragma unroll
            for (int q2 = 0; q2 < 16; q2++){
                union{ ull uu; float f[2]; } w2; w2.uu = u[q2];
                acc2 = fmaf(w2.f[0], rt[2*(p0+q2)],   acc2);
                acc2 = fmaf(w2.f[1], rt[2*(p0+q2)+1], acc2);
            }
        }
        if (tid < 128) sA[i] = acc2; else sB[i] = acc2;
    }
    __syncthreads();
    if (tid < 2){
        float* v = tid ? sB : sA;
        float m = -1e30f;
        for (int k = 0; k < 128; k++) m = fmaxf(m, v[k]);
        float su2 = 0.f;
        for (int k = 0; k < 128; k++){ float e = __expf(v[k]-m); v[k]=e; su2+=e; }
        float inv = 1.0f/su2;
        for (int k = 0; k < 128; k++) v[k] *= inv;
    }
    __syncthreads();
    {   // bet[col] = sum_i sA[i]*Hr[i][col]; alp[col] = sum_i sB[i]*Hl[i][col]
        const float* HrF = (const float*)HuR;
        const float* HlF = (const float*)HuL;
        float b = 0.f, al = 0.f;
        for (int i0 = 0; i0 < 128; i0 += 16){
            float ur[16], ulv[16];
            #pragma unroll
            for (int q2 = 0; q2 < 16; q2++){
                ur[q2]  = aloadf(&HrF[(size_t)(i0+q2)*256 + tid]);
                ulv[q2] = aloadf(&HlF[(size_t)(i0+q2)*256 + tid]);
            }
            #pragma unroll
            for (int q2 = 0; q2 < 16; q2++){
                b  = fmaf(sA[i0+q2], ur[q2],  b);
                al = fmaf(sB[i0+q2], ulv[q2], al);
            }
        }
        bet[tid] = b; alp[tid] = al;
    }
    __syncthreads();
    {
        float x = 0.f, y = 0.f;
        for (int k = 0; k < 256; k++){
            float w = Wattn[(size_t)k*256 + tid];
            x = fmaf(rl[k], w, x);
            y = fmaf(rr[k], w, y);
        }
        for (int k = 0; k < 256; k++){
            float w = Wattn[(size_t)(256+k)*256 + tid];
            x = fmaf(bet[k], w, x);
            y = fmaf(alp[k], w, y);
        }
        vl[tid] = x + battn[tid];
        vr[tid] = y + battn[tid];
    }
    __syncthreads();
    vec[tid]     = vl[tid]*vr[tid];
    vec[256+tid] = fabsf(vl[tid]-vr[tid]);
    __syncthreads();
    if (tid < 128){
        float acc2 = 0.f;
        for (int k = 0; k < 512; k++) acc2 = fmaf(vec[k], Wwh[(size_t)k*128+tid], acc2);
        hid[tid] = sigmf(acc2 + bwh[tid]);
    }
    __syncthreads();
    if (tid == 0){
        float lg[5];
        for (int c2 = 0; c2 < 5; c2++){
            float acc2 = bwp[c2];
            for (int k = 0; k < 128; k++) acc2 = fmaf(hid[k], Wwp[k*5+c2], acc2);
            lg[c2] = acc2;
        }
        float m = lg[0];
        for (int c2 = 1; c2 < 5; c2++) m = fmaxf(m, lg[c2]);
        float su2 = 0.f;
        for (int c2 = 0; c2 < 5; c2++) su2 += __expf(lg[c2]-m);
        float ls = logf(su2);
        for (int c2 = 0; c2 < 5; c2++) out[c2] = lg[c2]-m-ls;
    }
}

extern "C" void kernel_launch(void* const* d_in, const int* in_sizes, int n_in,
                              void* d_out, int out_size, void* d_ws, size_t ws_size,
                              hipStream_t stream) {
    const float* emb    = (const float*)d_in[0];
    const float* Wioux  = (const float*)d_in[1];
    const float* bioux  = (const float*)d_in[2];
    const float* Wiouh  = (const float*)d_in[3];
    const float* biouh  = (const float*)d_in[4];
    const float* Wfx    = (const float*)d_in[5];
    const float* bfx    = (const float*)d_in[6];
    const float* Wfh    = (const float*)d_in[7];
    const float* bfh    = (const float*)d_in[8];
    const float* Wattn  = (const float*)d_in[9];
    const float* battn  = (const float*)d_in[10];
    const float* Wwh    = (const float*)d_in[11];
    const float* bwh    = (const float*)d_in[12];
    const float* Wwp    = (const float*)d_in[13];
    const float* bwp    = (const float*)d_in[14];
    const int* linputs  = (const int*)d_in[15];
    const int* lparents = (const int*)d_in[16];
    const int* rinputs  = (const int*)d_in[17];
    const int* rparents = (const int*)d_in[18];
    float* ws  = (float*)d_ws;
    float* out = (float*)d_out;

    hipMemsetAsync((char*)d_ws + FLAG_BYTE, 0, 256, stream);
    k1_gemm<<<128, 256, 0, stream>>>(emb, Wioux, bioux, Wfx, bfx,
                                     linputs, rinputs, ws);
    k2_scan<<<32, 256, 0, stream>>>(Wiouh, biouh, Wfh, bfh, lparents, rparents,
                                    Wattn, battn, Wwh, bwh, Wwp, bwp, ws, out);
}

// Round 12
// 178.704 us; speedup vs baseline: 1.2757x; 1.2757x over previous
//
#include <hip/hip_runtime.h>
#include <math.h>

typedef unsigned long long ull;

// ws byte offsets
#define H_BYTE     0          // ull[2][128][128] = 256 KB (h pairs; canary 0xFF..F = unwritten)
#define IOUX_BYTE  262144     // float[2][16][128][64] = 1 MB (k1 -> k2)
#define FLAG_BYTE  1310720    // int fin[32] at ints 32..63

__device__ __forceinline__ float sigmf(float x){ return 1.0f/(1.0f+__expf(-x)); }
__device__ __forceinline__ float tanh_fast(float x){ float e=__expf(2.0f*x); return 1.0f-2.0f/(e+1.0f); }
__device__ __forceinline__ ull packf2(float lo, float hi){
    union{ float f[2]; ull u; } x; x.f[0]=lo; x.f[1]=hi; return x.u;
}
__device__ __forceinline__ ull aload64(const ull* p){
    return __hip_atomic_load(p, __ATOMIC_RELAXED, __HIP_MEMORY_SCOPE_AGENT);
}
__device__ __forceinline__ float aloadf(const float* p){
    return __hip_atomic_load(p, __ATOMIC_RELAXED, __HIP_MEMORY_SCOPE_AGENT);
}
__device__ __forceinline__ void astore64(ull* p, ull v){
    __hip_atomic_store(p, v, __ATOMIC_RELAXED, __HIP_MEMORY_SCOPE_AGENT);
}
__device__ __forceinline__ int aload32(const int* p){
    return __hip_atomic_load(p, __ATOMIC_RELAXED, __HIP_MEMORY_SCOPE_AGENT);
}
__device__ __forceinline__ void astore32(int* p, int v){
    __hip_atomic_store(p, v, __ATOMIC_RELAXED, __HIP_MEMORY_SCOPE_AGENT);
}

// 8 pipelined MALL-coherent 16B loads, one waitcnt (proven in R9).
__device__ __forceinline__ void stage8(const ull* p0, const ull* p1, const ull* p2, const ull* p3,
                                       const ull* p4, const ull* p5, const ull* p6, const ull* p7,
                                       float4* r){
    asm volatile(
        "global_load_dwordx4 %0, %8, off sc0 sc1\n\t"
        "global_load_dwordx4 %1, %9, off sc0 sc1\n\t"
        "global_load_dwordx4 %2, %10, off sc0 sc1\n\t"
        "global_load_dwordx4 %3, %11, off sc0 sc1\n\t"
        "global_load_dwordx4 %4, %12, off sc0 sc1\n\t"
        "global_load_dwordx4 %5, %13, off sc0 sc1\n\t"
        "global_load_dwordx4 %6, %14, off sc0 sc1\n\t"
        "global_load_dwordx4 %7, %15, off sc0 sc1\n\t"
        "s_waitcnt vmcnt(0)"
        : "=&v"(r[0]), "=&v"(r[1]), "=&v"(r[2]), "=&v"(r[3]),
          "=&v"(r[4]), "=&v"(r[5]), "=&v"(r[6]), "=&v"(r[7])
        : "v"(p0), "v"(p1), "v"(p2), "v"(p3), "v"(p4), "v"(p5), "v"(p6), "v"(p7)
        : "memory");
    __builtin_amdgcn_sched_barrier(0);
}

// ---------------------------------------------------------------------------
// K1: input GEMM + H canary fill. 128 blocks = tree(2) x sub(16) x q(4).
// dst[tree*16+sub][node][64]: cols 0..47 = i|o|u (16 each), 48..63 = fx.
// ---------------------------------------------------------------------------
__global__ __launch_bounds__(256) void k1_gemm(
        const float* __restrict__ emb,
        const float* __restrict__ Wioux, const float* __restrict__ bioux,
        const float* __restrict__ Wfx,   const float* __restrict__ bfx,
        const int* __restrict__ linputs, const int* __restrict__ rinputs,
        float* __restrict__ ws){
    int bid  = blockIdx.x;
    int tid = threadIdx.x;
    // canary-fill this block's 2KB slice of H2 (k1 completes before k2 launches)
    {
        ull* Hc = (ull*)((char*)ws + H_BYTE) + (size_t)bid*256;
        Hc[tid] = ~0ull;
        if (tid < 0) return;   // keep structure simple
    }
    int tree = bid >> 6;
    int sub  = (bid >> 2) & 15;
    int q    = bid & 3;
    int n0   = q * 32;
    const int* inp = tree ? rinputs : linputs;
    float* dst = (float*)((char*)ws + IOUX_BYTE) + (size_t)(tree*16+sub)*128*64;

    __shared__ float Xs[32][513];
    __shared__ int toks[32];
    if (tid < 32) toks[tid] = inp[n0 + tid];
    __syncthreads();
    {
        int r = tid & 31, seg = tid >> 5;
        const float* src = emb + (size_t)toks[r]*512 + seg*64;
        #pragma unroll
        for (int ii = 0; ii < 16; ii++){
            float4 v = ((const float4*)src)[ii];
            Xs[r][seg*64 + ii*4 + 0] = v.x;
            Xs[r][seg*64 + ii*4 + 1] = v.y;
            Xs[r][seg*64 + ii*4 + 2] = v.z;
            Xs[r][seg*64 + ii*4 + 3] = v.w;
        }
    }
    __syncthreads();
    int c  = tid & 63;
    int ng = tid >> 6;
    int g = c >> 4, jj = c & 15;
    const float* Wcol; int ld; float bias;
    if (g < 3){ int col = g*256 + sub*16 + jj; Wcol = Wioux + col; ld = 768; bias = bioux[col]; }
    else      { int col = sub*16 + jj;         Wcol = Wfx + col;   ld = 256; bias = bfx[col]; }
    float acc[8] = {0,0,0,0,0,0,0,0};
    #pragma unroll 4
    for (int k = 0; k < 512; k++){
        float w = Wcol[(size_t)k*ld];
        #pragma unroll
        for (int i = 0; i < 8; i++) acc[i] = fmaf(Xs[ng*8+i][k], w, acc[i]);
    }
    #pragma unroll
    for (int i = 0; i < 8; i++)
        dst[(size_t)(n0 + ng*8 + i)*64 + c] = acc[i] + bias;
}

// ---------------------------------------------------------------------------
// K2: canary-dataflow TreeLSTM. 32 blocks (16/tree) x 256 threads, fused head.
// Consumers poll the H DATA itself (canary = 0xFFFFFFFF dwords, impossible
// for real h). No prog counters, no level flags, no publish drains.
// ---------------------------------------------------------------------------
__global__ __launch_bounds__(256, 1) void k2_scan(
        const float* __restrict__ Wiouh, const float* __restrict__ biouh,
        const float* __restrict__ Wfh,   const float* __restrict__ bfh,
        const int* __restrict__ lparents, const int* __restrict__ rparents,
        const float* __restrict__ Wattn, const float* __restrict__ battn,
        const float* __restrict__ Wwh,   const float* __restrict__ bwh,
        const float* __restrict__ Wwp,   const float* __restrict__ bwp,
        float* __restrict__ ws, float* __restrict__ out){

    int bid = blockIdx.x;
    int tree = bid >> 4;
    int sub  = bid & 15;
    int slice = sub * 16;
    const int* parents = tree ? rparents : lparents;

    ull* H2all = (ull*)((char*)ws + H_BYTE);
    ull* H2 = H2all + (size_t)tree*128*128;
    const float* iosrc = (const float*)((char*)ws + IOUX_BYTE) + (size_t)(tree*16+sub)*128*64;
    int* flagB = (int*)((char*)ws + FLAG_BYTE);
    int* fin   = flagB + 32;

    // k-swizzle: km(k) = (k>>4)*20 + (k&15)
    __shared__ float hv[32][320];        // staged child h rows
    __shared__ float hsin[16][321];      // per-parent child-h sums
    __shared__ float red[4][48][17];     // cross-wave reduce
    __shared__ float FCtmp[32][17];
    __shared__ float fcin[16][17];
    __shared__ float cc[128][17];        // c per node (own cols)
    __shared__ float ioufL[128][68];     // 0..47 iou slice, 48..63 fx slice
    __shared__ int par[128], rnd[128], order[128], kids[128];
    __shared__ int rstart[129], kstart[129], cnt[129];
    __shared__ int clist[128], cpar[128];
    __shared__ int coff[17];
    __shared__ int changed;

    int tid = threadIdx.x;
    int a = tid >> 4;       // k-group / parent-slot
    int j = tid & 15;       // col
    int jcol = slice + j;

    // ---- weights -> registers ----
    float Wi[16], Wo[16], Wu[16], Wf[16];
    #pragma unroll
    for (int kk = 0; kk < 16; kk++){
        int k = a*16 + kk;
        Wi[kk] = Wiouh[(size_t)k*768 + jcol];
        Wo[kk] = Wiouh[(size_t)k*768 + 256 + jcol];
        Wu[kk] = Wiouh[(size_t)k*768 + 512 + jcol];
        Wf[kk] = Wfh[(size_t)k*256 + jcol];
    }
    float bioI = biouh[jcol], bioO = biouh[256+jcol], bioU = biouh[512+jcol];
    float bfv  = bfh[jcol];

    // ---- iou/fx slice -> LDS ----
    for (int i = tid; i < 128*16; i += 256){
        int n = i >> 4, f4 = i & 15;
        float4 v = ((const float4*)(iosrc + (size_t)n*64))[f4];
        int c0 = f4*4;
        ioufL[n][c0+0]=v.x; ioufL[n][c0+1]=v.y; ioufL[n][c0+2]=v.z; ioufL[n][c0+3]=v.w;
    }

    // ---- tree structure (block-local, deterministic) ----
    if (tid < 128){ par[tid] = parents[tid]; rnd[tid] = 0; }
    __syncthreads();
    for(;;){
        if (tid==0) changed = 0;
        __syncthreads();
        if (tid < 128){
            int p = par[tid];
            if (p < 128){
                int v = rnd[tid] + 1;
                if (atomicMax(&rnd[p], v) < v) changed = 1;
            }
        }
        __syncthreads();
        int done = (changed == 0);
        __syncthreads();
        if (done) break;
    }
    int nr = rnd[127] + 1;

    if (tid <= 128) cnt[tid] = 0;
    __syncthreads();
    if (tid < 128) atomicAdd(&cnt[rnd[tid]], 1);
    __syncthreads();
    if (tid==0){ int s2=0; for(int r2=0;r2<128;r2++){ rstart[r2]=s2; s2+=cnt[r2]; } rstart[128]=s2; }
    __syncthreads();
    if (tid < 128){
        int r2 = rnd[tid], rk = 0;
        for (int t2 = 0; t2 < tid; t2++) rk += (rnd[t2]==r2);
        order[rstart[r2]+rk] = tid;
    }
    __syncthreads();
    if (tid <= 128) cnt[tid] = 0;
    __syncthreads();
    if (tid < 128) atomicAdd(&cnt[par[tid]], 1);
    __syncthreads();
    if (tid==0){ int s2=0; for(int t2=0;t2<=128;t2++){ kstart[t2]=s2; s2+=cnt[t2]; } }
    __syncthreads();
    if (tid < 128){
        int p = par[tid], rk = 0;
        for (int t2 = 0; t2 < tid; t2++) rk += (par[t2]==p);
        kids[kstart[p]+rk] = tid;
    }
    __syncthreads();

    // ---- level 0: leaves ----
    {
        int rs = rstart[0], re = rstart[1];
        for (int b0 = rs; b0 < re; b0 += 16){
            int t = (b0 + a < re) ? order[b0 + a] : -1;
            float h = 0.f;
            if (t >= 0){
                float iv = ioufL[t][j]    + bioI;
                float ov = ioufL[t][16+j] + bioO;
                float uv = ioufL[t][32+j] + bioU;
                float cv = sigmf(iv) * tanh_fast(uv);
                h = sigmf(ov) * tanh_fast(cv);
                cc[t][j] = cv;
            }
            float hp = __shfl_xor(h, 1);
            if (t >= 0 && (j & 1) == 0)
                astore64(&H2[(size_t)t*128 + (slice>>1) + (j>>1)], packf2(h, hp));
        }
    }

    // ---- levels 1..nr-1: pure canary dataflow ----
    for (int r = 1; r < nr; r++){
        int rs = rstart[r], re = rstart[r+1];
        for (int b0 = rs; b0 < re; b0 += 16){
            int nn = re - b0; if (nn > 16) nn = 16;
            for (int i = tid; i < 16*321; i += 256) (&hsin[0][0])[i] = 0.f;
            fcin[a][j] = 0.f;
            if (tid == 0){
                int s2 = 0;
                for (int i2 = 0; i2 < 16; i2++){
                    coff[i2] = s2;
                    if (i2 < nn){ int t2 = order[b0+i2]; s2 += kstart[t2+1]-kstart[t2]; }
                }
                coff[16] = s2;
            }
            __syncthreads();
            if (tid < nn){
                int t2 = order[b0+tid];
                int o = coff[tid];
                for (int ci = kstart[t2]; ci < kstart[t2+1]; ci++, o++){
                    clist[o] = kids[ci]; cpar[o] = t2;
                }
            }
            __syncthreads();
            int M = coff[16];

            for (int cb = 0; cb < M; cb += 32){
                int mm = M - cb; if (mm > 32) mm = 32;
                {   // stage up to 32 rows: poll the DATA until no canary dwords
                    int c16 = tid & 63;
                    int rw  = tid >> 6;
                    int k0 = c16 * 4;
                    int km = (k0 >> 4)*20 + (k0 & 15);
                    const ull* pp[8];
                    #pragma unroll
                    for (int p = 0; p < 8; p++){
                        int s = p*4 + rw;
                        int idx = (s < mm) ? clist[cb+s] : clist[cb];
                        pp[p] = H2 + (size_t)idx*128 + c16*2;
                    }
                    float4 rr[8];
                    for(;;){
                        stage8(pp[0],pp[1],pp[2],pp[3],pp[4],pp[5],pp[6],pp[7], rr);
                        bool ok = true;
                        #pragma unroll
                        for (int p = 0; p < 8; p++){
                            int s = p*4 + rw;
                            if (s < mm){
                                uint4 u = *(uint4*)&rr[p];
                                ok = ok && (u.x != 0xFFFFFFFFu) && (u.y != 0xFFFFFFFFu)
                                        && (u.z != 0xFFFFFFFFu) && (u.w != 0xFFFFFFFFu);
                            }
                        }
                        if (ok) break;
                        __builtin_amdgcn_s_sleep(1);
                    }
                    #pragma unroll
                    for (int p = 0; p < 8; p++){
                        int s = p*4 + rw;
                        if (s < mm) *(float4*)&hv[s][km] = rr[p];
                    }
                }
                __syncthreads();
                // f matvec
                for (int s = 0; s < mm; s++){
                    const float* row = &hv[s][a*20];
                    float acc2 = 0.f;
                    #pragma unroll
                    for (int kk = 0; kk < 16; kk++) acc2 = fmaf(Wf[kk], row[kk], acc2);
                    acc2 += __shfl_xor(acc2, 16);
                    acc2 += __shfl_xor(acc2, 32);
                    if ((a & 3) == 0) red[tid>>6][s][j] = acc2;
                }
                __syncthreads();
                // f gates -> FCtmp
                for (int pass = 0; pass*16 < mm; pass++){
                    int s = pass*16 + a;
                    if (s < mm){
                        int o = cb + s;
                        float sf = red[0][s][j]+red[1][s][j]+red[2][s][j]+red[3][s][j];
                        float f = sigmf(sf + bfv + ioufL[cpar[o]][48+j]);
                        FCtmp[s][j] = f * cc[clist[o]][j];
                    }
                }
                __syncthreads();
                // accumulate per parent slot a, k-group j
                {
                    int o0 = coff[a]   > cb    ? coff[a]   : cb;
                    int o1 = coff[a+1] < cb+mm ? coff[a+1] : cb+mm;
                    float* dst = &hsin[a][j*20];
                    float fa = 0.f;
                    for (int o = o0; o < o1; o++){
                        int s = o - cb;
                        const float* src = &hv[s][j*20];
                        #pragma unroll
                        for (int kk = 0; kk < 16; kk++) dst[kk] += src[kk];
                        fa += FCtmp[s][j];
                    }
                    fcin[a][j] += fa;
                }
                __syncthreads();
            }

            // iou matvec
            for (int n = 0; n < nn; n++){
                const float* row = &hsin[n][a*20];
                float x=0.f, y=0.f, z=0.f;
                #pragma unroll
                for (int kk = 0; kk < 16; kk++){
                    float v = row[kk];
                    x = fmaf(Wi[kk], v, x);
                    y = fmaf(Wo[kk], v, y);
                    z = fmaf(Wu[kk], v, z);
                }
                x += __shfl_xor(x,16); x += __shfl_xor(x,32);
                y += __shfl_xor(y,16); y += __shfl_xor(y,32);
                z += __shfl_xor(z,16); z += __shfl_xor(z,32);
                if ((a & 3) == 0){
                    int w = tid >> 6;
                    red[w][n][j]    = x;
                    red[w][16+n][j] = y;
                    red[w][32+n][j] = z;
                }
            }
            __syncthreads();
            // gates + publish (no drain needed: data IS the flag)
            {
                int t = (a < nn) ? order[b0+a] : -1;
                float h = 0.f;
                if (t >= 0){
                    float si = red[0][a][j]+red[1][a][j]+red[2][a][j]+red[3][a][j];
                    float so = red[0][16+a][j]+red[1][16+a][j]+red[2][16+a][j]+red[3][16+a][j];
                    float su = red[0][32+a][j]+red[1][32+a][j]+red[2][32+a][j]+red[3][32+a][j];
                    float iv = si + ioufL[t][j]    + bioI;
                    float ov = so + ioufL[t][16+j] + bioO;
                    float uv = su + ioufL[t][32+j] + bioU;
                    float cv = fmaf(sigmf(iv), tanh_fast(uv), fcin[a][j]);
                    h = sigmf(ov) * tanh_fast(cv);
                    cc[t][j] = cv;
                }
                float hp = __shfl_xor(h, 1);
                if (t >= 0 && (j & 1) == 0)
                    astore64(&H2[(size_t)t*128 + (slice>>1) + (j>>1)], packf2(h, hp));
            }
            __syncthreads();   // LDS reuse protection only
        }
    }

    // ---- fin + fused head (block 0) ----
    if (tid == 0) astore32(&fin[bid], 1);
    if (bid != 0) return;
    if (tid < 64){
        for(;;){
            int v = (tid < 32) ? aload32(&fin[tid]) : 1;
            if (__all((tid < 32) ? (v == 1) : 1)) break;
            __builtin_amdgcn_s_sleep(2);
        }
    }
    __syncthreads();

    float* F  = &hv[0][0];
    float* rl = F,        *rr  = F + 256;
    float* sA = F + 512,  *sB  = F + 640;
    float* bet= F + 768,  *alp = F + 1024;
    float* vl = F + 1280, *vr  = F + 1536;
    float* vec= F + 1792, *hid = F + 2304;
    const ull* HuL = H2all;
    const ull* HuR = H2all + (size_t)128*128;

    {   // roots
        union{ ull u; float f[2]; } w2;
        if (tid < 128){
            w2.u = aload64(&HuL[(size_t)127*128 + tid]);
            rl[2*tid] = w2.f[0]; rl[2*tid+1] = w2.f[1];
        } else {
            int p = tid - 128;
            w2.u = aload64(&HuR[(size_t)127*128 + p]);
            rr[2*p] = w2.f[0]; rr[2*p+1] = w2.f[1];
        }
    }
    __syncthreads();
    {   // sA[i] = Hl_root . Hr[i] ; sB[i] = Hl[i] . Hr_root
        int i = tid & 127;
        const ull* row = (tid < 128) ? &HuR[(size_t)i*128] : &HuL[(size_t)i*128];
        const float* rt = (tid < 128) ? rl : rr;
        float acc2 = 0.f;
        for (int p0 = 0; p0 < 128; p0 += 16){
            ull u[16];
            #pragma unroll
            for (int q2 = 0; q2 < 16; q2++) u[q2] = aload64(&row[p0+q2]);
            #pragma unroll
            for (int q2 = 0; q2 < 16; q2++){
                union{ ull uu; float f[2]; } w2; w2.uu = u[q2];
                acc2 = fmaf(w2.f[0], rt[2*(p0+q2)],   acc2);
                acc2 = fmaf(w2.f[1], rt[2*(p0+q2)+1], acc2);
            }
        }
        if (tid < 128) sA[i] = acc2; else sB[i] = acc2;
    }
    __syncthreads();
    if (tid < 2){
        float* v = tid ? sB : sA;
        float m = -1e30f;
        for (int k = 0; k < 128; k++) m = fmaxf(m, v[k]);
        float su2 = 0.f;
        for (int k = 0; k < 128; k++){ float e = __expf(v[k]-m); v[k]=e; su2+=e; }
        float inv = 1.0f/su2;
        for (int k = 0; k < 128; k++) v[k] *= inv;
    }
    __syncthreads();
    {   // bet[col] = sum_i sA[i]*Hr[i][col]; alp[col] = sum_i sB[i]*Hl[i][col]
        const float* HrF = (const float*)HuR;
        const float* HlF = (const float*)HuL;
        float b = 0.f, al = 0.f;
        for (int i0 = 0; i0 < 128; i0 += 16){
            float ur[16], ulv[16];
            #pragma unroll
            for (int q2 = 0; q2 < 16; q2++){
                ur[q2]  = aloadf(&HrF[(size_t)(i0+q2)*256 + tid]);
                ulv[q2] = aloadf(&HlF[(size_t)(i0+q2)*256 + tid]);
            }
            #pragma unroll
            for (int q2 = 0; q2 < 16; q2++){
                b  = fmaf(sA[i0+q2], ur[q2],  b);
                al = fmaf(sB[i0+q2], ulv[q2], al);
            }
        }
        bet[tid] = b; alp[tid] = al;
    }
    __syncthreads();
    {
        float x = 0.f, y = 0.f;
        for (int k = 0; k < 256; k++){
            float w = Wattn[(size_t)k*256 + tid];
            x = fmaf(rl[k], w, x);
            y = fmaf(rr[k], w, y);
        }
        for (int k = 0; k < 256; k++){
            float w = Wattn[(size_t)(256+k)*256 + tid];
            x = fmaf(bet[k], w, x);
            y = fmaf(alp[k], w, y);
        }
        vl[tid] = x + battn[tid];
        vr[tid] = y + battn[tid];
    }
    __syncthreads();
    vec[tid]     = vl[tid]*vr[tid];
    vec[256+tid] = fabsf(vl[tid]-vr[tid]);
    __syncthreads();
    if (tid < 128){
        float acc2 = 0.f;
        for (int k = 0; k < 512; k++) acc2 = fmaf(vec[k], Wwh[(size_t)k*128+tid], acc2);
        hid[tid] = sigmf(acc2 + bwh[tid]);
    }
    __syncthreads();
    if (tid == 0){
        float lg[5];
        for (int c2 = 0; c2 < 5; c2++){
            float acc2 = bwp[c2];
            for (int k = 0; k < 128; k++) acc2 = fmaf(hid[k], Wwp[k*5+c2], acc2);
            lg[c2] = acc2;
        }
        float m = lg[0];
        for (int c2 = 1; c2 < 5; c2++) m = fmaxf(m, lg[c2]);
        float su2 = 0.f;
        for (int c2 = 0; c2 < 5; c2++) su2 += __expf(lg[c2]-m);
        float ls = logf(su2);
        for (int c2 = 0; c2 < 5; c2++) out[c2] = lg[c2]-m-ls;
    }
}

extern "C" void kernel_launch(void* const* d_in, const int* in_sizes, int n_in,
                              void* d_out, int out_size, void* d_ws, size_t ws_size,
                              hipStream_t stream) {
    const float* emb    = (const float*)d_in[0];
    const float* Wioux  = (const float*)d_in[1];
    const float* bioux  = (const float*)d_in[2];
    const float* Wiouh  = (const float*)d_in[3];
    const float* biouh  = (const float*)d_in[4];
    const float* Wfx    = (const float*)d_in[5];
    const float* bfx    = (const float*)d_in[6];
    const float* Wfh    = (const float*)d_in[7];
    const float* bfh    = (const float*)d_in[8];
    const float* Wattn  = (const float*)d_in[9];
    const float* battn  = (const float*)d_in[10];
    const float* Wwh    = (const float*)d_in[11];
    const float* bwh    = (const float*)d_in[12];
    const float* Wwp    = (const float*)d_in[13];
    const float* bwp    = (const float*)d_in[14];
    const int* linputs  = (const int*)d_in[15];
    const int* lparents = (const int*)d_in[16];
    const int* rinputs  = (const int*)d_in[17];
    const int* rparents = (const int*)d_in[18];
    float* ws  = (float*)d_ws;
    float* out = (float*)d_out;

    hipMemsetAsync((char*)d_ws + FLAG_BYTE, 0, 256, stream);
    k1_gemm<<<128, 256, 0, stream>>>(emb, Wioux, bioux, Wfx, bfx,
                                     linputs, rinputs, ws);
    k2_scan<<<32, 256, 0, stream>>>(Wiouh, biouh, Wfh, bfh, lparents, rparents,
                                    Wattn, battn, Wwh, bwh, Wwp, bwp, ws, out);
}